// Round 11
// baseline (466.303 us; speedup 1.0000x reference)
//
#include <hip/hip_runtime.h>

#define NN 100000
#define NE 1600000
#define F 64
#define NSB ((NN + 255) / 256)   // 391 scan blocks
#define NTB ((NN + 127) / 128)   // 782 node tiles

typedef float f32x4 __attribute__((ext_vector_type(4)));
typedef float f32x2 __attribute__((ext_vector_type(2)));
typedef short bf16x8 __attribute__((ext_vector_type(8)));

__device__ inline unsigned short f2bf(float f) {          // RTNE float->bf16
    unsigned u = __builtin_bit_cast(unsigned, f);
    u = (u + 0x7fffu + ((u >> 16) & 1u)) >> 16;
    return (unsigned short)u;
}
__device__ inline float bf2f(unsigned short b) { return __builtin_bit_cast(float, (unsigned)b << 16); }
__device__ inline float bflo(unsigned u) { return __builtin_bit_cast(float, u << 16); }
__device__ inline float bfhi(unsigned u) { return __builtin_bit_cast(float, u & 0xffff0000u); }

__device__ inline bf16x8 pack8(const f32x4 v0, const f32x4 v1) {
    bf16x8 pk;
    pk[0] = (short)f2bf(v0[0]); pk[1] = (short)f2bf(v0[1]);
    pk[2] = (short)f2bf(v0[2]); pk[3] = (short)f2bf(v0[3]);
    pk[4] = (short)f2bf(v1[0]); pk[5] = (short)f2bf(v1[1]);
    pk[6] = (short)f2bf(v1[2]); pk[7] = (short)f2bf(v1[3]);
    return pk;
}

// ---------------- node transform via bf16 MFMA ----------------
// grid (NTB, 3): blockIdx.x = 128-row tile, blockIdx.y = weight matrix.
// m==0 blocks zero their counts slice (node precedes edge's fused hist).
__global__ __launch_bounds__(256, 2) void node_kernel(
    const float* __restrict__ nfeats,
    const float* __restrict__ W_node, const float* __restrict__ b_node,
    const float* __restrict__ W_ni,   const float* __restrict__ W_nj,
    unsigned short* __restrict__ f_ni16, unsigned short* __restrict__ f_nj16,
    unsigned short* __restrict__ h16, int* __restrict__ counts)
{
    __shared__ bf16x8 As8[128 * 8];   // 16 KB: A tile, later f32 D half-tile [128][32]
    __shared__ bf16x8 Ws8[64 * 8];    //  8 KB
    float* Df = reinterpret_cast<float*>(As8);

    const int t = threadIdx.x;
    const int w = t >> 6, lane = t & 63;
    const int tile0 = blockIdx.x * 128;
    const int m = blockIdx.y;

    if (m == 0 && t < 128 && tile0 + t < NN) counts[tile0 + t] = 0;

    {
        const float* Wp = (m == 0) ? W_ni : (m == 1) ? W_nj : W_node;
        const f32x4* gw = reinterpret_cast<const f32x4*>(Wp);
#pragma unroll
        for (int i = 0; i < 2; ++i) {
            const int c = i * 256 + t;
            const int row = c >> 3, slot = c & 7;
            Ws8[row * 8 + (slot ^ (row & 7))] = pack8(gw[2 * c], gw[2 * c + 1]);
        }
    }
    {
        const f32x4* gsrc = reinterpret_cast<const f32x4*>(nfeats + (size_t)tile0 * F);
#pragma unroll
        for (int i = 0; i < 4; ++i) {
            const int c = i * 256 + t;
            const int row = c >> 3, slot = c & 7;
            f32x4 v0 = f32x4{0.f, 0.f, 0.f, 0.f}, v1 = f32x4{0.f, 0.f, 0.f, 0.f};
            if (tile0 + row < NN) { v0 = gsrc[2 * c]; v1 = gsrc[2 * c + 1]; }
            As8[row * 8 + (slot ^ (row & 7))] = pack8(v0, v1);
        }
    }
    __syncthreads();

    bf16x8 af[2][2];
#pragma unroll
    for (int mt = 0; mt < 2; ++mt)
#pragma unroll
        for (int ks = 0; ks < 2; ++ks) {
            const int row = w * 32 + mt * 16 + (lane & 15);
            const int kslot = ks * 4 + (lane >> 4);
            af[mt][ks] = As8[row * 8 + (kslot ^ (row & 7))];
        }

    bf16x8 bfr[4][2];
#pragma unroll
    for (int nt = 0; nt < 4; ++nt)
#pragma unroll
        for (int ks = 0; ks < 2; ++ks) {
            const int c = nt * 16 + (lane & 15);
            const int kslot = ks * 4 + (lane >> 4);
            bfr[nt][ks] = Ws8[c * 8 + (kslot ^ (c & 7))];
        }

    f32x4 acc[2][4];
#pragma unroll
    for (int mt = 0; mt < 2; ++mt)
#pragma unroll
        for (int nt = 0; nt < 4; ++nt) acc[mt][nt] = f32x4{0.f, 0.f, 0.f, 0.f};
#pragma unroll
    for (int ks = 0; ks < 2; ++ks)
#pragma unroll
        for (int mt = 0; mt < 2; ++mt)
#pragma unroll
            for (int nt = 0; nt < 4; ++nt)
                acc[mt][nt] = __builtin_amdgcn_mfma_f32_16x16x32_bf16(
                    af[mt][ks], bfr[nt][ks], acc[mt][nt], 0, 0, 0);

    __syncthreads();

    unsigned short* outp = (m == 0) ? f_ni16 : (m == 1) ? f_nj16 : h16;

#pragma unroll
    for (int half = 0; half < 2; ++half) {
#pragma unroll
        for (int mt = 0; mt < 2; ++mt)
#pragma unroll
            for (int ntl = 0; ntl < 2; ++ntl) {
#pragma unroll
                for (int r = 0; r < 4; ++r) {
                    const int row = w * 32 + mt * 16 + (lane >> 4) * 4 + r;
                    const int col = ntl * 16 + (lane & 15);
                    float v = acc[mt][half * 2 + ntl][r];
                    if (m == 2) v += b_node[half * 32 + col];
                    Df[row * 32 + ((col + row) & 31)] = v;
                }
            }
        __syncthreads();

#pragma unroll
        for (int i = 0; i < 2; ++i) {
            const int idx = i * 256 + t;
            const int row = idx >> 2;
            const int c8 = (idx & 3) << 3;
            if (tile0 + row < NN) {
                const float* b = Df + row * 32;
                uint4 pk;
                unsigned u[4];
#pragma unroll
                for (int p = 0; p < 4; ++p) {
                    const unsigned lo = f2bf(b[(c8 + 2 * p + 0 + row) & 31]);
                    const unsigned hi = f2bf(b[(c8 + 2 * p + 1 + row) & 31]);
                    u[p] = lo | (hi << 16);
                }
                pk.x = u[0]; pk.y = u[1]; pk.z = u[2]; pk.w = u[3];
                *reinterpret_cast<uint4*>(outp + (size_t)(tile0 + row) * F + half * 32 + c8) = pk;
            }
        }
        __syncthreads();
    }
}

// ---------------- edge update via bf16 MFMA, half-split (register-lean) ----------------
// Per half: bfr 2 n-tiles (16 regs) + acc[4][2] (32) + gathers 64B (32);
// af (32) lives across halves. Target ~150 VGPR -> 3 blocks/CU.
__global__ __launch_bounds__(256, 3) void edge_kernel(
    const float* __restrict__ efeats,
    const int* __restrict__ src, const int* __restrict__ dst,
    const unsigned short* __restrict__ f_ni16, const unsigned short* __restrict__ f_nj16,
    const float* __restrict__ W_fij, const float* __restrict__ bias,
    float* __restrict__ f_out, int* __restrict__ counts)
{
    __shared__ bf16x8 As8[256 * 8];   // 32 KB: A tile / f32 D half-tile
    __shared__ bf16x8 Ws8[64 * 8];    //  8 KB
    float* Df = reinterpret_cast<float*>(As8);

    const int t = threadIdx.x;
    const int w = t >> 6, lane = t & 63;
    const int tile0 = blockIdx.x * 256;
    const int e = tile0 + t;
    const int s = src[e], d = dst[e];

    {
        const f32x4* gw = reinterpret_cast<const f32x4*>(W_fij);
#pragma unroll
        for (int i = 0; i < 2; ++i) {
            const int c = i * 256 + t;
            const int row = c >> 3, slot = c & 7;
            Ws8[row * 8 + (slot ^ (row & 7))] = pack8(gw[2 * c], gw[2 * c + 1]);
        }
    }
    {
        const f32x4* gsrc = reinterpret_cast<const f32x4*>(efeats + (size_t)tile0 * F);
#pragma unroll
        for (int i = 0; i < 8; ++i) {
            const int c = i * 256 + t;
            const int row = c >> 3, slot = c & 7;
            const f32x4 v0 = __builtin_nontemporal_load(gsrc + 2 * c);
            const f32x4 v1 = __builtin_nontemporal_load(gsrc + 2 * c + 1);
            As8[row * 8 + (slot ^ (row & 7))] = pack8(v0, v1);
        }
    }
    atomicAdd(&counts[d], 1);        // fused histogram
    __syncthreads();

    // A fragments, loaded once
    bf16x8 af[4][2];
#pragma unroll
    for (int mt = 0; mt < 4; ++mt)
#pragma unroll
        for (int ks = 0; ks < 2; ++ks) {
            const int row = w * 64 + mt * 16 + (lane & 15);
            const int kslot = ks * 4 + (lane >> 4);
            af[mt][ks] = As8[row * 8 + (kslot ^ (row & 7))];
        }

    const uint4* gi = reinterpret_cast<const uint4*>(f_ni16 + (size_t)s * F);
    const uint4* gj = reinterpret_cast<const uint4*>(f_nj16 + (size_t)d * F);
    f32x4* gout = reinterpret_cast<f32x4*>(f_out + (size_t)tile0 * F);

#pragma unroll
    for (int half = 0; half < 2; ++half) {
        // B fragments for this half's 2 n-tiles
        bf16x8 bfr[2][2];
#pragma unroll
        for (int ntl = 0; ntl < 2; ++ntl)
#pragma unroll
            for (int ks = 0; ks < 2; ++ks) {
                const int c = (half * 2 + ntl) * 16 + (lane & 15);
                const int kslot = ks * 4 + (lane >> 4);
                bfr[ntl][ks] = Ws8[c * 8 + (kslot ^ (c & 7))];
            }
        // gathers for this half (64 B per table row); latency hides under MFMAs
        uint4 vni[4], vnj[4];
#pragma unroll
        for (int i = 0; i < 4; ++i) { vni[i] = gi[half * 4 + i]; vnj[i] = gj[half * 4 + i]; }

        f32x4 acc[4][2];
#pragma unroll
        for (int mt = 0; mt < 4; ++mt)
#pragma unroll
            for (int ntl = 0; ntl < 2; ++ntl) acc[mt][ntl] = f32x4{0.f, 0.f, 0.f, 0.f};
#pragma unroll
        for (int ks = 0; ks < 2; ++ks)
#pragma unroll
            for (int mt = 0; mt < 4; ++mt)
#pragma unroll
                for (int ntl = 0; ntl < 2; ++ntl)
                    acc[mt][ntl] = __builtin_amdgcn_mfma_f32_16x16x32_bf16(
                        af[mt][ks], bfr[ntl][ks], acc[mt][ntl], 0, 0, 0);

        __syncthreads();    // all As8/Df readers done (af loads / previous stage-out)

        // scatter -> rotate-swizzled f32 D-tile [256][32]
#pragma unroll
        for (int mt = 0; mt < 4; ++mt)
#pragma unroll
            for (int ntl = 0; ntl < 2; ++ntl) {
#pragma unroll
                for (int r = 0; r < 4; ++r) {
                    const int row = w * 64 + mt * 16 + (lane >> 4) * 4 + r;
                    const int col = ntl * 16 + (lane & 15);
                    Df[row * 32 + ((col + row) & 31)] = acc[mt][ntl][r];
                }
            }
        __syncthreads();

        // per-thread row finish: +gathers +bias, leaky
        float* rb = Df + t * 32;
#pragma unroll
        for (int c = 0; c < 32; ++c) {
            float v = rb[(c + t) & 31];
            const unsigned wi = vni[c >> 3][(c >> 1) & 3];
            const unsigned wj = vnj[c >> 3][(c >> 1) & 3];
            v += (c & 1) ? bfhi(wi) : bflo(wi);
            v += (c & 1) ? bfhi(wj) : bflo(wj);
            v += bias[half * 32 + c];
            v = (v > 0.f) ? v : 0.01f * v;
            rb[(c + t) & 31] = v;
        }
        __syncthreads();

        // stage-out: swizzled LDS reads, linear nt f32x4 stores
#pragma unroll
        for (int i = 0; i < 8; ++i) {
            const int idx = i * 256 + t;
            const int row = idx >> 3;
            const int c4 = (idx & 7) << 2;
            const float* b = Df + row * 32;
            f32x4 v;
            v[0] = b[(c4 + 0 + row) & 31];
            v[1] = b[(c4 + 1 + row) & 31];
            v[2] = b[(c4 + 2 + row) & 31];
            v[3] = b[(c4 + 3 + row) & 31];
            __builtin_nontemporal_store(v, gout + row * 16 + half * 8 + (idx & 7));
        }
        __syncthreads();
    }
}

// ---------------- CSR scan, 3-phase device-wide ----------------
__global__ __launch_bounds__(256) void scan1_kernel(
    const int* __restrict__ counts, int* __restrict__ offsets, int* __restrict__ blocksums)
{
    __shared__ int sd[256];
    const int t = threadIdx.x;
    const int i = blockIdx.x * 256 + t;
    const int v = (i < NN) ? counts[i] : 0;
    sd[t] = v;
    __syncthreads();
#pragma unroll
    for (int off = 1; off < 256; off <<= 1) {
        const int x = (t >= off) ? sd[t - off] : 0;
        __syncthreads();
        sd[t] += x;
        __syncthreads();
    }
    if (i < NN) offsets[i] = sd[t] - v;
    if (t == 255) blocksums[blockIdx.x] = sd[255];
}

__global__ __launch_bounds__(512) void scan2_kernel(
    const int* __restrict__ blocksums, int* __restrict__ blockpref)
{
    __shared__ int sd[512];
    const int t = threadIdx.x;
    const int v = (t < NSB) ? blocksums[t] : 0;
    sd[t] = v;
    __syncthreads();
#pragma unroll
    for (int off = 1; off < 512; off <<= 1) {
        const int x = (t >= off) ? sd[t - off] : 0;
        __syncthreads();
        sd[t] += x;
        __syncthreads();
    }
    if (t < NSB) blockpref[t] = sd[t] - v;
}

__global__ __launch_bounds__(256) void scan3_kernel(
    int* __restrict__ offsets, const int* __restrict__ blockpref, int* __restrict__ cursor)
{
    const int i = blockIdx.x * 256 + threadIdx.x;
    if (i < NN) {
        const int o = offsets[i] + blockpref[blockIdx.x];
        offsets[i] = o;
        cursor[i] = o;
    }
    if (i == 0) offsets[NN] = NE;
}

// ---------------- CSR placement ----------------
__global__ __launch_bounds__(256) void place_kernel(
    const int* __restrict__ src, const int* __restrict__ dst,
    int* __restrict__ cursor, int* __restrict__ eidx)
{
    const int e = blockIdx.x * 256 + threadIdx.x;
    if (e >= NE) return;
    const int pos = atomicAdd(&cursor[dst[e]], 1);
    eidx[pos] = src[e];
}

// ---------------- aggregation: wave per node, 2 edges/step ----------------
// lane loads uint (2 cols); lanes 0-31 even edge, 32-63 odd edge;
// fold halves via shfl_xor(32); lanes<32 store float2.
__global__ __launch_bounds__(256) void gather_kernel(
    const unsigned short* __restrict__ h16, const int* __restrict__ offsets,
    const int* __restrict__ eidx, float* __restrict__ h_out)
{
    const int n = blockIdx.x * 4 + (threadIdx.x >> 6);
    const int lane = threadIdx.x & 63;
    if (n >= NN) return;
    const int beg = offsets[n], end = offsets[n + 1];
    const int colp = (lane & 31) * 2;
    const int sel = lane >> 5;
    float a0 = 0.f, a1 = 0.f;
    int k = beg;
    for (; k + 4 <= end; k += 4) {
        const int e0 = eidx[k + sel];
        const int e1 = eidx[k + 2 + sel];
        const unsigned u0 = *reinterpret_cast<const unsigned*>(h16 + (size_t)e0 * F + colp);
        const unsigned u1 = *reinterpret_cast<const unsigned*>(h16 + (size_t)e1 * F + colp);
        a0 += bflo(u0) + bflo(u1);
        a1 += bfhi(u0) + bfhi(u1);
    }
    for (; k + 2 <= end; k += 2) {
        const int e0 = eidx[k + sel];
        const unsigned u0 = *reinterpret_cast<const unsigned*>(h16 + (size_t)e0 * F + colp);
        a0 += bflo(u0);
        a1 += bfhi(u0);
    }
    if (k < end && sel == 0) {      // last single edge: lower half-wave only
        const int e0 = eidx[k];
        const unsigned u0 = *reinterpret_cast<const unsigned*>(h16 + (size_t)e0 * F + colp);
        a0 += bflo(u0);
        a1 += bfhi(u0);
    }
    a0 += __shfl_xor(a0, 32, 64);
    a1 += __shfl_xor(a1, 32, 64);
    if (sel == 0) {
        const float dg = fmaxf((float)(end - beg), 1.0f);
        f32x2 o;
        o[0] = a0 / dg;
        o[1] = a1 / dg;
        __builtin_nontemporal_store(o, reinterpret_cast<f32x2*>(h_out + (size_t)n * F + colp));
    }
}

extern "C" void kernel_launch(void* const* d_in, const int* in_sizes, int n_in,
                              void* d_out, int out_size, void* d_ws, size_t ws_size,
                              hipStream_t stream)
{
    const float* nfeats = (const float*)d_in[0];
    const float* efeats = (const float*)d_in[1];
    const int*   src    = (const int*)  d_in[2];
    const int*   dst    = (const int*)  d_in[3];
    const float* W_node = (const float*)d_in[4];
    const float* b_node = (const float*)d_in[5];
    const float* W_ni   = (const float*)d_in[6];
    const float* W_nj   = (const float*)d_in[7];
    const float* W_fij  = (const float*)d_in[8];
    const float* bias   = (const float*)d_in[9];

    float* h_out = (float*)d_out;                   // [NN, F]
    float* f_out = (float*)d_out + (size_t)NN * F;  // [NE, F]

    unsigned short* f_ni16 = (unsigned short*)d_ws;            // bf16 tables
    unsigned short* f_nj16 = f_ni16 + (size_t)NN * F;
    unsigned short* h16    = f_nj16 + (size_t)NN * F;
    int*   offsets = (int*)(h16 + (size_t)NN * F);  // NN+1
    int*   cursor  = offsets + (NN + 1);            // NN
    int*   counts  = cursor + NN;                   // NN
    int*   eidx    = counts + NN;                   // NE
    int*   blocksums = eidx + NE;                   // NSB
    int*   blockpref = blocksums + NSB;             // NSB
    const size_t need = ((size_t)3 * NN * F) * sizeof(unsigned short)
                      + ((size_t)(3 * NN + 1) + NE + 2 * NSB) * sizeof(int);
    if (ws_size < need) return;

    node_kernel<<<dim3(NTB, 3), 256, 0, stream>>>(nfeats, W_node, b_node, W_ni, W_nj,
                                                  f_ni16, f_nj16, h16, counts);
    edge_kernel<<<NE / 256, 256, 0, stream>>>(efeats, src, dst, f_ni16, f_nj16, W_fij, bias,
                                              f_out, counts);
    scan1_kernel<<<NSB, 256, 0, stream>>>(counts, offsets, blocksums);
    scan2_kernel<<<1, 512, 0, stream>>>(blocksums, blockpref);
    scan3_kernel<<<NSB, 256, 0, stream>>>(offsets, blockpref, cursor);
    place_kernel<<<(NE + 255) / 256, 256, 0, stream>>>(src, dst, cursor, eidx);
    gather_kernel<<<(NN + 3) / 4, 256, 0, stream>>>(h16, offsets, eidx, h_out);
}

// Round 12
// 427.532 us; speedup vs baseline: 1.0907x; 1.0907x over previous
//
#include <hip/hip_runtime.h>

#define NN 100000
#define NE 1600000
#define F 64
#define NSB ((NN + 255) / 256)   // 391 scan blocks
#define NTB ((NN + 127) / 128)   // 782 node tiles

typedef float f32x4 __attribute__((ext_vector_type(4)));
typedef float f32x2 __attribute__((ext_vector_type(2)));
typedef short bf16x8 __attribute__((ext_vector_type(8)));

__device__ inline unsigned short f2bf(float f) {          // RTNE float->bf16
    unsigned u = __builtin_bit_cast(unsigned, f);
    u = (u + 0x7fffu + ((u >> 16) & 1u)) >> 16;
    return (unsigned short)u;
}
__device__ inline float bf2f(unsigned short b) { return __builtin_bit_cast(float, (unsigned)b << 16); }
__device__ inline float bflo(unsigned u) { return __builtin_bit_cast(float, u << 16); }
__device__ inline float bfhi(unsigned u) { return __builtin_bit_cast(float, u & 0xffff0000u); }

__device__ inline bf16x8 pack8(const f32x4 v0, const f32x4 v1) {
    bf16x8 pk;
    pk[0] = (short)f2bf(v0[0]); pk[1] = (short)f2bf(v0[1]);
    pk[2] = (short)f2bf(v0[2]); pk[3] = (short)f2bf(v0[3]);
    pk[4] = (short)f2bf(v1[0]); pk[5] = (short)f2bf(v1[1]);
    pk[6] = (short)f2bf(v1[2]); pk[7] = (short)f2bf(v1[3]);
    return pk;
}

// ---------------- node transform via bf16 MFMA ----------------
// grid (NTB, 3): blockIdx.x = 128-row tile, blockIdx.y = weight matrix.
// m==0 blocks zero their counts slice (node precedes edge's fused hist).
__global__ __launch_bounds__(256, 2) void node_kernel(
    const float* __restrict__ nfeats,
    const float* __restrict__ W_node, const float* __restrict__ b_node,
    const float* __restrict__ W_ni,   const float* __restrict__ W_nj,
    unsigned short* __restrict__ f_ni16, unsigned short* __restrict__ f_nj16,
    unsigned short* __restrict__ h16, int* __restrict__ counts)
{
    __shared__ bf16x8 As8[128 * 8];   // 16 KB: A tile, later f32 D half-tile [128][32]
    __shared__ bf16x8 Ws8[64 * 8];    //  8 KB
    float* Df = reinterpret_cast<float*>(As8);

    const int t = threadIdx.x;
    const int w = t >> 6, lane = t & 63;
    const int tile0 = blockIdx.x * 128;
    const int m = blockIdx.y;

    if (m == 0 && t < 128 && tile0 + t < NN) counts[tile0 + t] = 0;

    {
        const float* Wp = (m == 0) ? W_ni : (m == 1) ? W_nj : W_node;
        const f32x4* gw = reinterpret_cast<const f32x4*>(Wp);
#pragma unroll
        for (int i = 0; i < 2; ++i) {
            const int c = i * 256 + t;
            const int row = c >> 3, slot = c & 7;
            Ws8[row * 8 + (slot ^ (row & 7))] = pack8(gw[2 * c], gw[2 * c + 1]);
        }
    }
    {
        const f32x4* gsrc = reinterpret_cast<const f32x4*>(nfeats + (size_t)tile0 * F);
#pragma unroll
        for (int i = 0; i < 4; ++i) {
            const int c = i * 256 + t;
            const int row = c >> 3, slot = c & 7;
            f32x4 v0 = f32x4{0.f, 0.f, 0.f, 0.f}, v1 = f32x4{0.f, 0.f, 0.f, 0.f};
            if (tile0 + row < NN) { v0 = gsrc[2 * c]; v1 = gsrc[2 * c + 1]; }
            As8[row * 8 + (slot ^ (row & 7))] = pack8(v0, v1);
        }
    }
    __syncthreads();

    bf16x8 af[2][2];
#pragma unroll
    for (int mt = 0; mt < 2; ++mt)
#pragma unroll
        for (int ks = 0; ks < 2; ++ks) {
            const int row = w * 32 + mt * 16 + (lane & 15);
            const int kslot = ks * 4 + (lane >> 4);
            af[mt][ks] = As8[row * 8 + (kslot ^ (row & 7))];
        }

    bf16x8 bfr[4][2];
#pragma unroll
    for (int nt = 0; nt < 4; ++nt)
#pragma unroll
        for (int ks = 0; ks < 2; ++ks) {
            const int c = nt * 16 + (lane & 15);
            const int kslot = ks * 4 + (lane >> 4);
            bfr[nt][ks] = Ws8[c * 8 + (kslot ^ (c & 7))];
        }

    f32x4 acc[2][4];
#pragma unroll
    for (int mt = 0; mt < 2; ++mt)
#pragma unroll
        for (int nt = 0; nt < 4; ++nt) acc[mt][nt] = f32x4{0.f, 0.f, 0.f, 0.f};
#pragma unroll
    for (int ks = 0; ks < 2; ++ks)
#pragma unroll
        for (int mt = 0; mt < 2; ++mt)
#pragma unroll
            for (int nt = 0; nt < 4; ++nt)
                acc[mt][nt] = __builtin_amdgcn_mfma_f32_16x16x32_bf16(
                    af[mt][ks], bfr[nt][ks], acc[mt][nt], 0, 0, 0);

    __syncthreads();

    unsigned short* outp = (m == 0) ? f_ni16 : (m == 1) ? f_nj16 : h16;

#pragma unroll
    for (int half = 0; half < 2; ++half) {
#pragma unroll
        for (int mt = 0; mt < 2; ++mt)
#pragma unroll
            for (int ntl = 0; ntl < 2; ++ntl) {
#pragma unroll
                for (int r = 0; r < 4; ++r) {
                    const int row = w * 32 + mt * 16 + (lane >> 4) * 4 + r;
                    const int col = ntl * 16 + (lane & 15);
                    float v = acc[mt][half * 2 + ntl][r];
                    if (m == 2) v += b_node[half * 32 + col];
                    Df[row * 32 + ((col + row) & 31)] = v;
                }
            }
        __syncthreads();

#pragma unroll
        for (int i = 0; i < 2; ++i) {
            const int idx = i * 256 + t;
            const int row = idx >> 2;
            const int c8 = (idx & 3) << 3;
            if (tile0 + row < NN) {
                const float* b = Df + row * 32;
                uint4 pk;
                unsigned u[4];
#pragma unroll
                for (int p = 0; p < 4; ++p) {
                    const unsigned lo = f2bf(b[(c8 + 2 * p + 0 + row) & 31]);
                    const unsigned hi = f2bf(b[(c8 + 2 * p + 1 + row) & 31]);
                    u[p] = lo | (hi << 16);
                }
                pk.x = u[0]; pk.y = u[1]; pk.z = u[2]; pk.w = u[3];
                *reinterpret_cast<uint4*>(outp + (size_t)(tile0 + row) * F + half * 32 + c8) = pk;
            }
        }
        __syncthreads();
    }
}

// ---------------- edge update via bf16 MFMA, half-split, prefetched gathers ----------------
// launch_bounds(256,2): no VGPR squeeze (R11's (256,3) -> 84 VGPR + 112 MB spill writes).
// Gathers issued early: half0 before the staging barrier, half1 under half0's epilogue.
__global__ __launch_bounds__(256, 2) void edge_kernel(
    const float* __restrict__ efeats,
    const int* __restrict__ src, const int* __restrict__ dst,
    const unsigned short* __restrict__ f_ni16, const unsigned short* __restrict__ f_nj16,
    const float* __restrict__ W_fij, const float* __restrict__ bias,
    float* __restrict__ f_out, int* __restrict__ counts)
{
    __shared__ bf16x8 As8[256 * 8];   // 32 KB: A tile / f32 D half-tile
    __shared__ bf16x8 Ws8[64 * 8];    //  8 KB (separate; live all kernel)
    float* Df = reinterpret_cast<float*>(As8);

    const int t = threadIdx.x;
    const int w = t >> 6, lane = t & 63;
    const int tile0 = blockIdx.x * 256;
    const int e = tile0 + t;
    const int s = src[e], d = dst[e];

    const uint4* gi = reinterpret_cast<const uint4*>(f_ni16 + (size_t)s * F);
    const uint4* gj = reinterpret_cast<const uint4*>(f_nj16 + (size_t)d * F);

    // half-0 gathers: issued first, consumed after the MFMA block (max latency cover)
    uint4 vni[4], vnj[4];
#pragma unroll
    for (int i = 0; i < 4; ++i) { vni[i] = gi[i]; vnj[i] = gj[i]; }

    {
        const f32x4* gw = reinterpret_cast<const f32x4*>(W_fij);
#pragma unroll
        for (int i = 0; i < 2; ++i) {
            const int c = i * 256 + t;
            const int row = c >> 3, slot = c & 7;
            Ws8[row * 8 + (slot ^ (row & 7))] = pack8(gw[2 * c], gw[2 * c + 1]);
        }
    }
    {
        const f32x4* gsrc = reinterpret_cast<const f32x4*>(efeats + (size_t)tile0 * F);
#pragma unroll
        for (int i = 0; i < 8; ++i) {
            const int c = i * 256 + t;
            const int row = c >> 3, slot = c & 7;
            const f32x4 v0 = __builtin_nontemporal_load(gsrc + 2 * c);
            const f32x4 v1 = __builtin_nontemporal_load(gsrc + 2 * c + 1);
            As8[row * 8 + (slot ^ (row & 7))] = pack8(v0, v1);
        }
    }
    atomicAdd(&counts[d], 1);        // fused histogram
    __syncthreads();

    // A fragments (once) + half-0 B fragments
    bf16x8 af[4][2];
#pragma unroll
    for (int mt = 0; mt < 4; ++mt)
#pragma unroll
        for (int ks = 0; ks < 2; ++ks) {
            const int row = w * 64 + mt * 16 + (lane & 15);
            const int kslot = ks * 4 + (lane >> 4);
            af[mt][ks] = As8[row * 8 + (kslot ^ (row & 7))];
        }
    bf16x8 bfr[2][2];
#pragma unroll
    for (int ntl = 0; ntl < 2; ++ntl)
#pragma unroll
        for (int ks = 0; ks < 2; ++ks) {
            const int c = ntl * 16 + (lane & 15);
            const int kslot = ks * 4 + (lane >> 4);
            bfr[ntl][ks] = Ws8[c * 8 + (kslot ^ (c & 7))];
        }

    f32x4 acc[4][2];
#pragma unroll
    for (int mt = 0; mt < 4; ++mt)
#pragma unroll
        for (int ntl = 0; ntl < 2; ++ntl) acc[mt][ntl] = f32x4{0.f, 0.f, 0.f, 0.f};
#pragma unroll
    for (int ks = 0; ks < 2; ++ks)
#pragma unroll
        for (int mt = 0; mt < 4; ++mt)
#pragma unroll
            for (int ntl = 0; ntl < 2; ++ntl)
                acc[mt][ntl] = __builtin_amdgcn_mfma_f32_16x16x32_bf16(
                    af[mt][ks], bfr[ntl][ks], acc[mt][ntl], 0, 0, 0);

    __syncthreads();    // all af reads of As8 done -> Df usable

    f32x4* gout = reinterpret_cast<f32x4*>(f_out + (size_t)tile0 * F);

    // ---- half 0 epilogue ----
#pragma unroll
    for (int mt = 0; mt < 4; ++mt)
#pragma unroll
        for (int ntl = 0; ntl < 2; ++ntl)
#pragma unroll
            for (int r = 0; r < 4; ++r) {
                const int row = w * 64 + mt * 16 + (lane >> 4) * 4 + r;
                const int col = ntl * 16 + (lane & 15);
                Df[row * 32 + ((col + row) & 31)] = acc[mt][ntl][r];
            }
    // half-1 gathers: issued here, consumed after half-1 MFMAs (covered by epilogue below)
    uint4 nni[4], nnj[4];
#pragma unroll
    for (int i = 0; i < 4; ++i) { nni[i] = gi[4 + i]; nnj[i] = gj[4 + i]; }
    __syncthreads();

    {
        float* rb = Df + t * 32;
#pragma unroll
        for (int c = 0; c < 32; ++c) {
            float v = rb[(c + t) & 31];
            const unsigned wi = vni[c >> 3][(c >> 1) & 3];
            const unsigned wj = vnj[c >> 3][(c >> 1) & 3];
            v += (c & 1) ? bfhi(wi) : bflo(wi);
            v += (c & 1) ? bfhi(wj) : bflo(wj);
            v += bias[c];
            v = (v > 0.f) ? v : 0.01f * v;
            rb[(c + t) & 31] = v;
        }
    }
    __syncthreads();
#pragma unroll
    for (int i = 0; i < 8; ++i) {
        const int idx = i * 256 + t;
        const int row = idx >> 3;
        const int c4 = (idx & 7) << 2;
        const float* b = Df + row * 32;
        f32x4 v;
        v[0] = b[(c4 + 0 + row) & 31];
        v[1] = b[(c4 + 1 + row) & 31];
        v[2] = b[(c4 + 2 + row) & 31];
        v[3] = b[(c4 + 3 + row) & 31];
        __builtin_nontemporal_store(v, gout + row * 16 + (idx & 7));
    }
    __syncthreads();    // Df free for half 1

    // ---- half 1: B frags, MFMAs, epilogue ----
#pragma unroll
    for (int ntl = 0; ntl < 2; ++ntl)
#pragma unroll
        for (int ks = 0; ks < 2; ++ks) {
            const int c = (2 + ntl) * 16 + (lane & 15);
            const int kslot = ks * 4 + (lane >> 4);
            bfr[ntl][ks] = Ws8[c * 8 + (kslot ^ (c & 7))];
        }
#pragma unroll
    for (int mt = 0; mt < 4; ++mt)
#pragma unroll
        for (int ntl = 0; ntl < 2; ++ntl) acc[mt][ntl] = f32x4{0.f, 0.f, 0.f, 0.f};
#pragma unroll
    for (int ks = 0; ks < 2; ++ks)
#pragma unroll
        for (int mt = 0; mt < 4; ++mt)
#pragma unroll
            for (int ntl = 0; ntl < 2; ++ntl)
                acc[mt][ntl] = __builtin_amdgcn_mfma_f32_16x16x32_bf16(
                    af[mt][ks], bfr[ntl][ks], acc[mt][ntl], 0, 0, 0);

#pragma unroll
    for (int mt = 0; mt < 4; ++mt)
#pragma unroll
        for (int ntl = 0; ntl < 2; ++ntl)
#pragma unroll
            for (int r = 0; r < 4; ++r) {
                const int row = w * 64 + mt * 16 + (lane >> 4) * 4 + r;
                const int col = ntl * 16 + (lane & 15);
                Df[row * 32 + ((col + row) & 31)] = acc[mt][ntl][r];
            }
    __syncthreads();
    {
        float* rb = Df + t * 32;
#pragma unroll
        for (int c = 0; c < 32; ++c) {
            float v = rb[(c + t) & 31];
            const unsigned wi = nni[c >> 3][(c >> 1) & 3];
            const unsigned wj = nnj[c >> 3][(c >> 1) & 3];
            v += (c & 1) ? bfhi(wi) : bflo(wi);
            v += (c & 1) ? bfhi(wj) : bflo(wj);
            v += bias[32 + c];
            v = (v > 0.f) ? v : 0.01f * v;
            rb[(c + t) & 31] = v;
        }
    }
    __syncthreads();
#pragma unroll
    for (int i = 0; i < 8; ++i) {
        const int idx = i * 256 + t;
        const int row = idx >> 3;
        const int c4 = (idx & 7) << 2;
        const float* b = Df + row * 32;
        f32x4 v;
        v[0] = b[(c4 + 0 + row) & 31];
        v[1] = b[(c4 + 1 + row) & 31];
        v[2] = b[(c4 + 2 + row) & 31];
        v[3] = b[(c4 + 3 + row) & 31];
        __builtin_nontemporal_store(v, gout + row * 16 + 8 + (idx & 7));
    }
}

// ---------------- CSR scan, 3-phase device-wide ----------------
__global__ __launch_bounds__(256) void scan1_kernel(
    const int* __restrict__ counts, int* __restrict__ offsets, int* __restrict__ blocksums)
{
    __shared__ int sd[256];
    const int t = threadIdx.x;
    const int i = blockIdx.x * 256 + t;
    const int v = (i < NN) ? counts[i] : 0;
    sd[t] = v;
    __syncthreads();
#pragma unroll
    for (int off = 1; off < 256; off <<= 1) {
        const int x = (t >= off) ? sd[t - off] : 0;
        __syncthreads();
        sd[t] += x;
        __syncthreads();
    }
    if (i < NN) offsets[i] = sd[t] - v;
    if (t == 255) blocksums[blockIdx.x] = sd[255];
}

__global__ __launch_bounds__(512) void scan2_kernel(
    const int* __restrict__ blocksums, int* __restrict__ blockpref)
{
    __shared__ int sd[512];
    const int t = threadIdx.x;
    const int v = (t < NSB) ? blocksums[t] : 0;
    sd[t] = v;
    __syncthreads();
#pragma unroll
    for (int off = 1; off < 512; off <<= 1) {
        const int x = (t >= off) ? sd[t - off] : 0;
        __syncthreads();
        sd[t] += x;
        __syncthreads();
    }
    if (t < NSB) blockpref[t] = sd[t] - v;
}

__global__ __launch_bounds__(256) void scan3_kernel(
    int* __restrict__ offsets, const int* __restrict__ blockpref, int* __restrict__ cursor)
{
    const int i = blockIdx.x * 256 + threadIdx.x;
    if (i < NN) {
        const int o = offsets[i] + blockpref[blockIdx.x];
        offsets[i] = o;
        cursor[i] = o;
    }
    if (i == 0) offsets[NN] = NE;
}

// ---------------- CSR placement ----------------
__global__ __launch_bounds__(256) void place_kernel(
    const int* __restrict__ src, const int* __restrict__ dst,
    int* __restrict__ cursor, int* __restrict__ eidx)
{
    const int e = blockIdx.x * 256 + threadIdx.x;
    if (e >= NE) return;
    const int pos = atomicAdd(&cursor[dst[e]], 1);
    eidx[pos] = src[e];
}

// ---------------- aggregation: wave per node, 2 edges/step ----------------
__global__ __launch_bounds__(256) void gather_kernel(
    const unsigned short* __restrict__ h16, const int* __restrict__ offsets,
    const int* __restrict__ eidx, float* __restrict__ h_out)
{
    const int n = blockIdx.x * 4 + (threadIdx.x >> 6);
    const int lane = threadIdx.x & 63;
    if (n >= NN) return;
    const int beg = offsets[n], end = offsets[n + 1];
    const int colp = (lane & 31) * 2;
    const int sel = lane >> 5;
    float a0 = 0.f, a1 = 0.f;
    int k = beg;
    for (; k + 4 <= end; k += 4) {
        const int e0 = eidx[k + sel];
        const int e1 = eidx[k + 2 + sel];
        const unsigned u0 = *reinterpret_cast<const unsigned*>(h16 + (size_t)e0 * F + colp);
        const unsigned u1 = *reinterpret_cast<const unsigned*>(h16 + (size_t)e1 * F + colp);
        a0 += bflo(u0) + bflo(u1);
        a1 += bfhi(u0) + bfhi(u1);
    }
    for (; k + 2 <= end; k += 2) {
        const int e0 = eidx[k + sel];
        const unsigned u0 = *reinterpret_cast<const unsigned*>(h16 + (size_t)e0 * F + colp);
        a0 += bflo(u0);
        a1 += bfhi(u0);
    }
    if (k < end && sel == 0) {
        const int e0 = eidx[k];
        const unsigned u0 = *reinterpret_cast<const unsigned*>(h16 + (size_t)e0 * F + colp);
        a0 += bflo(u0);
        a1 += bfhi(u0);
    }
    a0 += __shfl_xor(a0, 32, 64);
    a1 += __shfl_xor(a1, 32, 64);
    if (sel == 0) {
        const float dg = fmaxf((float)(end - beg), 1.0f);
        f32x2 o;
        o[0] = a0 / dg;
        o[1] = a1 / dg;
        __builtin_nontemporal_store(o, reinterpret_cast<f32x2*>(h_out + (size_t)n * F + colp));
    }
}

extern "C" void kernel_launch(void* const* d_in, const int* in_sizes, int n_in,
                              void* d_out, int out_size, void* d_ws, size_t ws_size,
                              hipStream_t stream)
{
    const float* nfeats = (const float*)d_in[0];
    const float* efeats = (const float*)d_in[1];
    const int*   src    = (const int*)  d_in[2];
    const int*   dst    = (const int*)  d_in[3];
    const float* W_node = (const float*)d_in[4];
    const float* b_node = (const float*)d_in[5];
    const float* W_ni   = (const float*)d_in[6];
    const float* W_nj   = (const float*)d_in[7];
    const float* W_fij  = (const float*)d_in[8];
    const float* bias   = (const float*)d_in[9];

    float* h_out = (float*)d_out;                   // [NN, F]
    float* f_out = (float*)d_out + (size_t)NN * F;  // [NE, F]

    unsigned short* f_ni16 = (unsigned short*)d_ws;            // bf16 tables
    unsigned short* f_nj16 = f_ni16 + (size_t)NN * F;
    unsigned short* h16    = f_nj16 + (size_t)NN * F;
    int*   offsets = (int*)(h16 + (size_t)NN * F);  // NN+1
    int*   cursor  = offsets + (NN + 1);            // NN
    int*   counts  = cursor + NN;                   // NN
    int*   eidx    = counts + NN;                   // NE
    int*   blocksums = eidx + NE;                   // NSB
    int*   blockpref = blocksums + NSB;             // NSB
    const size_t need = ((size_t)3 * NN * F) * sizeof(unsigned short)
                      + ((size_t)(3 * NN + 1) + NE + 2 * NSB) * sizeof(int);
    if (ws_size < need) return;

    node_kernel<<<dim3(NTB, 3), 256, 0, stream>>>(nfeats, W_node, b_node, W_ni, W_nj,
                                                  f_ni16, f_nj16, h16, counts);
    edge_kernel<<<NE / 256, 256, 0, stream>>>(efeats, src, dst, f_ni16, f_nj16, W_fij, bias,
                                              f_out, counts);
    scan1_kernel<<<NSB, 256, 0, stream>>>(counts, offsets, blocksums);
    scan2_kernel<<<1, 512, 0, stream>>>(blocksums, blockpref);
    scan3_kernel<<<NSB, 256, 0, stream>>>(offsets, blockpref, cursor);
    place_kernel<<<(NE + 255) / 256, 256, 0, stream>>>(src, dst, cursor, eidx);
    gather_kernel<<<(NN + 3) / 4, 256, 0, stream>>>(h16, offsets, eidx, h_out);
}